// Round 11
// baseline (186.952 us; speedup 1.0000x reference)
//
#include <hip/hip_runtime.h>

typedef short v8s __attribute__((ext_vector_type(8)));
typedef short v4s __attribute__((ext_vector_type(4)));
typedef float v4f __attribute__((ext_vector_type(4)));
typedef unsigned uint2v __attribute__((ext_vector_type(2)));
typedef unsigned short u16;

#define NSEQ 2048
#define CDIM 768
#define NH   16
#define DH   48
#define DP   64
#define MROWS 4096      // B*N
#define N3C  2304
#define BH   32         // B*H

#if __has_builtin(__builtin_amdgcn_exp2f)
#define EXP2(x) __builtin_amdgcn_exp2f(x)
#else
#define EXP2(x) exp2f(x)
#endif
#if __has_builtin(__builtin_amdgcn_rcpf)
#define RCP(x) __builtin_amdgcn_rcpf(x)
#else
#define RCP(x) (1.0f/(x))
#endif

__device__ __forceinline__ u16 f2bf(float f){
  unsigned u = __float_as_uint(f);
  u += 0x7FFFu + ((u>>16)&1u);      // RNE; inputs finite
  return (u16)(u>>16);
}
__device__ __forceinline__ unsigned pkbf(float a, float b){   // [lo=a, hi=b] bf16 pair, RNE
  unsigned x = __float_as_uint(a), y = __float_as_uint(b);
  x += 0x7FFFu + ((x>>16)&1u);
  y += 0x7FFFu + ((y>>16)&1u);
  return (x>>16) | (y & 0xFFFF0000u);
}

__device__ __forceinline__ void load_lds16(const u16* g, u16* l){
  __builtin_amdgcn_global_load_lds((const __attribute__((address_space(1))) void*)g,
                                   (__attribute__((address_space(3))) void*)l, 16, 0, 0);
}

// ---------------- K0: fused convert (x,qkv_w,proj_w -> bf16) + Q/K pad init ----------------
#define XN8  (MROWS*CDIM/8)                     // 393216
#define WN8  (N3C*CDIM/8)                       // 221184
#define PN8  (CDIM*CDIM/8)                      // 73728
#define CONVB ((XN8+WN8+PN8)/256)               // 2688 blocks
__global__ __launch_bounds__(256) void prep(const float* __restrict__ x, const float* __restrict__ w,
                                            const float* __restrict__ pw, u16* __restrict__ dst,
                                            u16* __restrict__ q, u16* __restrict__ k){
  int bid = blockIdx.x;
  if (bid < CONVB){
    int i = bid*256 + threadIdx.x;
    const float* src;
    if (i < XN8)            src = x  + (size_t)i*8;
    else if (i < XN8+WN8)   src = w  + (size_t)(i - XN8)*8;
    else                    src = pw + (size_t)(i - XN8 - WN8)*8;
    v4f f0 = ((const v4f*)src)[0];
    v4f f1 = ((const v4f*)src)[1];
    v8s o;
#pragma unroll
    for (int j = 0; j < 4; j++) ((u16*)&o)[j]   = f2bf(f0[j]);
#pragma unroll
    for (int j = 0; j < 4; j++) ((u16*)&o)[4+j] = f2bf(f1[j]);
    ((v8s*)dst)[i] = o;
  } else {
    int idx = (bid - CONVB)*256 + threadIdx.x;  // 512 blocks -> 131072 threads
    v8s z = (v8s){0,0,0,0,0,0,0,0};
    int r = idx >> 1, half = idx & 1;           // Q/K: 65536 rows, 2x16B pad per row
    *(v8s*)(q + (size_t)r*DP + DH + half*8) = z;
    *(v8s*)(k + (size_t)r*DP + DH + half*8) = z;
  }
}

// ================= K1: qkv GEMM, 128x128 tile, BK=64 (12 iters, half the barriers) =================
__global__ __launch_bounds__(256) void qkv_gemm(const u16* __restrict__ x, const u16* __restrict__ w,
                                                const float* __restrict__ bias,
                                                u16* __restrict__ q, u16* __restrict__ k, u16* __restrict__ v){
  __shared__ __align__(16) u16 As[128*64];      // 16 KB
  __shared__ __align__(16) u16 Bs[128*64];      // 16 KB
  const int wave = threadIdx.x >> 6;
  const int lane = threadIdx.x & 63;
  const int l15  = lane & 15;
  const int quad = lane >> 4;
  const int lo3  = l15 & 7;
  const int wm = wave & 1, wn = wave >> 1;
  const int m0 = blockIdx.x*128, n0 = blockIdx.y*128;

  // staging: 8-granule rows, pos p holds global granule p^(row&7); lane-only perm
  const int sr   = lane >> 3;                   // row within 8-row chunk
  const int soff = ((lane & 7) ^ (sr & 7)) * 8; // permuted source granule (u16 offset)

  v4f acc[4][4];
#pragma unroll
  for (int i = 0; i < 4; i++)
#pragma unroll
    for (int j = 0; j < 4; j++) acc[i][j] = (v4f){0.f,0.f,0.f,0.f};

  for (int kt = 0; kt < CDIM/64; kt++){
    const int k0 = kt*64;
    __syncthreads();
#pragma unroll
    for (int j = 0; j < 4; j++){
      int ch = wave*4 + j;                      // 8-row chunk 0..15
      int r  = ch*8 + sr;
      load_lds16(x + (size_t)(m0 + r)*CDIM + k0 + soff, &As[ch*512]);
      load_lds16(w + (size_t)(n0 + r)*CDIM + k0 + soff, &Bs[ch*512]);
    }
    __syncthreads();

#pragma unroll
    for (int ks = 0; ks < 2; ks++){
      v8s af[4], bf[4];
#pragma unroll
      for (int t = 0; t < 4; t++){
        int ra = wm*64 + t*16 + l15;
        af[t] = *(const v8s*)(&As[ra*64 + (((ks*4+quad) ^ lo3)<<3)]);
        int rb = wn*64 + t*16 + l15;
        bf[t] = *(const v8s*)(&Bs[rb*64 + (((ks*4+quad) ^ lo3)<<3)]);
      }
#pragma unroll
      for (int ti = 0; ti < 4; ti++)
#pragma unroll
        for (int tj = 0; tj < 4; tj++)
          acc[ti][tj] = __builtin_amdgcn_mfma_f32_16x16x32_bf16(af[ti], bf[tj], acc[ti][tj], 0, 0, 0);
    }
  }

  const float QS = 0.2082540589f;   // 1/sqrt(48) * log2(e)
#pragma unroll
  for (int tj = 0; tj < 4; tj++){
    const int c = n0 + wn*64 + tj*16 + l15;
    const float bv = bias[c];
    const int t = c / CDIM;
    const int rem = c - t*CDIM;
    const int h = rem / DH;
    const int d = rem - h*DH;
#pragma unroll
    for (int ti = 0; ti < 4; ti++){
#pragma unroll
      for (int r = 0; r < 4; r++){
        int m = m0 + wm*64 + ti*16 + quad*4 + r;
        int b_ = m >> 11;
        int n  = m & (NSEQ-1);
        float val = acc[ti][tj][r] + bv;
        if (t == 0) val *= QS;
        u16 o  = f2bf(val);
        int bhn = b_*NH + h;
        if (t == 0)      q[((size_t)bhn*NSEQ + n)*DP + d] = o;
        else if (t == 1) k[((size_t)bhn*NSEQ + n)*DP + d] = o;
        else             v[((size_t)bhn*DP + d)*NSEQ + n] = o;
      }
    }
  }
}

// ---------------- K2: flash attention (round-10 version, unchanged) ----------------
__global__ __launch_bounds__(256) void attn(const u16* __restrict__ q, const u16* __restrict__ k,
                                            const u16* __restrict__ v,
                                            float* __restrict__ oacc, float* __restrict__ lacc){
  __shared__ __align__(16) u16 Kl[64*64];
  __shared__ __align__(16) u16 Vl[48*64];
  __shared__ __align__(16) u16 Pl[4*2*1024];
  const int bh = blockIdx.x;
  const int qt = blockIdx.y;
  const int sp = blockIdx.z;
  const int wave = threadIdx.x >> 6;
  const int lane = threadIdx.x & 63;
  const int l15  = lane & 15;
  const int quad = lane >> 4;
  const int lo3  = l15 & 7;
  const u16* qb = q + (size_t)bh*NSEQ*DP;
  const u16* kb = k + (size_t)bh*NSEQ*DP;
  const u16* vb = v + (size_t)bh*DP*NSEQ;
  const int qm = qt*128 + wave*32;

  v8s qf[2][2];
#pragma unroll
  for (int si = 0; si < 2; si++)
#pragma unroll
    for (int ks = 0; ks < 2; ks++)
      qf[si][ks] = *(const v8s*)(qb + (size_t)(qm + si*16 + l15)*DP + ks*32 + quad*8);

  const short one = (short)0x3F80;
  const v8s vones = (l15 == 0) ? (v8s){one,one,one,one,one,one,one,one}
                               : (v8s){0,0,0,0,0,0,0,0};

  v4f o[2][4];
#pragma unroll
  for (int si = 0; si < 2; si++)
#pragma unroll
    for (int i = 0; i < 4; i++) o[si][i] = (v4f){0.f,0.f,0.f,0.f};

  const int sr  = lane >> 3;
  const int soff = ((lane & 7) ^ (sr & 7)) * 8;
  u16* Plw = Pl + wave*2048;

  for (int kt = sp*16; kt < sp*16 + 16; kt++){
    __syncthreads();
    {
#pragma unroll
      for (int p = 0; p < 2; p++){
        int row = p*32 + wave*8 + sr;
        load_lds16(kb + ((size_t)(kt*64 + row))*DP + soff, &Kl[(p*32 + wave*8)*64]);
      }
      {
        int row = wave*8 + sr;
        load_lds16(vb + (size_t)row*NSEQ + kt*64 + soff, &Vl[(wave*8)*64]);
      }
      if (wave < 2){
        int row = 32 + wave*8 + sr;
        load_lds16(vb + (size_t)row*NSEQ + kt*64 + soff, &Vl[(32 + wave*8)*64]);
      }
    }
    __syncthreads();

    v4f s[2][4];
#pragma unroll
    for (int nt = 0; nt < 4; nt++){
      int rrow = nt*16 + l15;
      v8s kf0 = *(const v8s*)(&Kl[rrow*64 + ((quad ^ lo3)<<3)]);
      v8s kf1 = *(const v8s*)(&Kl[rrow*64 + (((4+quad) ^ lo3)<<3)]);
      s[0][nt] = __builtin_amdgcn_mfma_f32_16x16x32_bf16(kf0, qf[0][0], (v4f){0.f,0.f,0.f,0.f}, 0, 0, 0);
      s[0][nt] = __builtin_amdgcn_mfma_f32_16x16x32_bf16(kf1, qf[0][1], s[0][nt], 0, 0, 0);
      s[1][nt] = __builtin_amdgcn_mfma_f32_16x16x32_bf16(kf0, qf[1][0], (v4f){0.f,0.f,0.f,0.f}, 0, 0, 0);
      s[1][nt] = __builtin_amdgcn_mfma_f32_16x16x32_bf16(kf1, qf[1][1], s[1][nt], 0, 0, 0);
    }

#pragma unroll
    for (int si = 0; si < 2; si++)
#pragma unroll
      for (int nt = 0; nt < 4; nt++){
        uint2v pw;
        pw.x = pkbf(EXP2(s[si][nt][0]), EXP2(s[si][nt][1]));
        pw.y = pkbf(EXP2(s[si][nt][2]), EXP2(s[si][nt][3]));
        int g = nt*2 + (quad>>1);
        *(uint2v*)(&Plw[si*1024 + l15*64 + ((g ^ lo3)<<3) + (quad&1)*4]) = pw;
      }

    v8s pa[2][2];
#pragma unroll
    for (int si = 0; si < 2; si++)
#pragma unroll
      for (int ks = 0; ks < 2; ks++){
        int ga = ks*4 + quad;
        pa[si][ks] = *(const v8s*)(&Plw[si*1024 + l15*64 + ((ga ^ lo3)<<3)]);
      }
#pragma unroll
    for (int dt = 0; dt < 3; dt++){
#pragma unroll
      for (int ks = 0; ks < 2; ks++){
        int row = dt*16 + l15;
        v8s vf = *(const v8s*)(&Vl[row*64 + (((ks*4+quad) ^ lo3)<<3)]);
        o[0][dt] = __builtin_amdgcn_mfma_f32_16x16x32_bf16(pa[0][ks], vf, o[0][dt], 0, 0, 0);
        o[1][dt] = __builtin_amdgcn_mfma_f32_16x16x32_bf16(pa[1][ks], vf, o[1][dt], 0, 0, 0);
      }
    }
#pragma unroll
    for (int ks = 0; ks < 2; ks++){
      o[0][3] = __builtin_amdgcn_mfma_f32_16x16x32_bf16(pa[0][ks], vones, o[0][3], 0, 0, 0);
      o[1][3] = __builtin_amdgcn_mfma_f32_16x16x32_bf16(pa[1][ks], vones, o[1][3], 0, 0, 0);
    }
  }

  const int b_ = bh / NH, h = bh % NH;
  float* oa = oacc + (size_t)sp*MROWS*CDIM;
  float* la = lacc + (size_t)sp*MROWS*NH;
#pragma unroll
  for (int si = 0; si < 2; si++){
#pragma unroll
    for (int r = 0; r < 4; r++){
      int rowg = b_*NSEQ + qm + si*16 + quad*4 + r;
#pragma unroll
      for (int dt = 0; dt < 3; dt++)
        oa[(size_t)rowg*CDIM + h*DH + dt*16 + l15] = o[si][dt][r];
      if (l15 == 0) la[rowg*NH + h] = o[si][3][r];
    }
  }
}

// ================= K3: proj GEMM, 64x128 tile, BK=64, fused combine+normalize =================
__global__ __launch_bounds__(256) void proj_gemm(const float* __restrict__ oacc,
                                                 const float* __restrict__ lacc,
                                                 const u16* __restrict__ w,
                                                 const float* __restrict__ bias, float* __restrict__ out){
  __shared__ __align__(16) u16 As[64*64];       // 8 KB
  __shared__ __align__(16) u16 Bs[128*64];      // 16 KB
  const int wave = threadIdx.x >> 6;
  const int lane = threadIdx.x & 63;
  const int l15  = lane & 15;
  const int quad = lane >> 4;
  const int lo3  = l15 & 7;
  const int wm = wave & 1, wn = wave >> 1;
  const int m0 = blockIdx.x*64, n0 = blockIdx.y*128;

  // B staging (async, lane-only perm)
  const int sr   = lane >> 3;
  const int soff = ((lane & 7) ^ (sr & 7)) * 8;
  // A combine: thread -> row ar, LDS granule pair (ap0, ap0+1)
  const int ar  = threadIdx.x >> 2;             // 0..63
  const int ap0 = (threadIdx.x & 3)*2;          // even LDS pos
  const int ag0 = ap0 ^ (ar & 7);               // global granule held at ap0; ap0+1 holds ag0^1
  const int rowg = m0 + ar;
  const float* oa0 = oacc + (size_t)rowg*CDIM;
  const float* oa1 = oacc + (size_t)MROWS*CDIM + (size_t)rowg*CDIM;

  v4f acc[2][4];
#pragma unroll
  for (int i = 0; i < 2; i++)
#pragma unroll
    for (int j = 0; j < 4; j++) acc[i][j] = (v4f){0.f,0.f,0.f,0.f};

  for (int kt = 0; kt < CDIM/64; kt++){
    const int k0 = kt*64;
    __syncthreads();
    {
      // A: combine two splits, normalize, pack 16 bf16, one b128 LDS write
      int c0 = k0 + ag0*8;
      int c1 = c0 ^ 8;                          // granule ag0^1
      unsigned h = (unsigned)c0 / (unsigned)DH; // pair lies in one 16-aligned chunk -> one h
      float l = lacc[rowg*NH + h] + lacc[MROWS*NH + rowg*NH + h];
      float inv = RCP(l);
      v4f a0 = *(const v4f*)(oa0 + c0);
      v4f a1 = *(const v4f*)(oa0 + c0 + 4);
      v4f a2 = *(const v4f*)(oa0 + c1);
      v4f a3 = *(const v4f*)(oa0 + c1 + 4);
      v4f b0 = *(const v4f*)(oa1 + c0);
      v4f b1 = *(const v4f*)(oa1 + c0 + 4);
      v4f b2 = *(const v4f*)(oa1 + c1);
      v4f b3 = *(const v4f*)(oa1 + c1 + 4);
      v8s ov;
#pragma unroll
      for (int j = 0; j < 4; j++) ((u16*)&ov)[j]    = f2bf((a0[j] + b0[j])*inv);
#pragma unroll
      for (int j = 0; j < 4; j++) ((u16*)&ov)[4+j]  = f2bf((a1[j] + b1[j])*inv);
      v8s ov2;
#pragma unroll
      for (int j = 0; j < 4; j++) ((u16*)&ov2)[j]   = f2bf((a2[j] + b2[j])*inv);
#pragma unroll
      for (int j = 0; j < 4; j++) ((u16*)&ov2)[4+j] = f2bf((a3[j] + b3[j])*inv);
      *(v8s*)(&As[ar*64 + ap0*8])     = ov;
      *(v8s*)(&As[ar*64 + ap0*8 + 8]) = ov2;
      // B: async staging, 16 chunks of 8 rows
#pragma unroll
      for (int j = 0; j < 4; j++){
        int ch = wave*4 + j;
        int rB = ch*8 + sr;
        load_lds16(w + (size_t)(n0 + rB)*CDIM + k0 + soff, &Bs[ch*512]);
      }
    }
    __syncthreads();

#pragma unroll
    for (int ks = 0; ks < 2; ks++){
      v8s af[2], bf[4];
#pragma unroll
      for (int t = 0; t < 2; t++){
        int rr = wm*32 + t*16 + l15;
        af[t] = *(const v8s*)(&As[rr*64 + (((ks*4+quad) ^ lo3)<<3)]);
      }
#pragma unroll
      for (int t = 0; t < 4; t++){
        int rb = wn*64 + t*16 + l15;
        bf[t] = *(const v8s*)(&Bs[rb*64 + (((ks*4+quad) ^ lo3)<<3)]);
      }
#pragma unroll
      for (int ti = 0; ti < 2; ti++)
#pragma unroll
        for (int tj = 0; tj < 4; tj++)
          acc[ti][tj] = __builtin_amdgcn_mfma_f32_16x16x32_bf16(af[ti], bf[tj], acc[ti][tj], 0, 0, 0);
    }
  }

#pragma unroll
  for (int tj = 0; tj < 4; tj++){
    const int c = n0 + wn*64 + tj*16 + l15;
    const float bv = bias[c];
#pragma unroll
    for (int ti = 0; ti < 2; ti++){
#pragma unroll
      for (int r = 0; r < 4; r++){
        int m = m0 + wm*32 + ti*16 + quad*4 + r;
        out[(size_t)m*CDIM + c] = acc[ti][tj][r] + bv;
      }
    }
  }
}

extern "C" void kernel_launch(void* const* d_in, const int* in_sizes, int n_in,
                              void* d_out, int out_size, void* d_ws, size_t ws_size,
                              hipStream_t stream){
  const float* x      = (const float*)d_in[0];
  const float* qkv_w  = (const float*)d_in[1];
  const float* qkv_b  = (const float*)d_in[2];
  const float* proj_w = (const float*)d_in[3];
  const float* proj_b = (const float*)d_in[4];
  float* out = (float*)d_out;

  // ws layout (u16 units)
  u16* xb  = (u16*)d_ws;                         // [4096][768] bf16
  u16* wb  = xb  + (size_t)MROWS*CDIM;           // [2304][768] bf16
  u16* pwb = wb  + (size_t)N3C*CDIM;             // [768][768]  bf16
  u16* q   = pwb + (size_t)CDIM*CDIM;            // [BH][NSEQ][DP]
  u16* k   = q + (size_t)BH*NSEQ*DP;
  u16* v   = k + (size_t)BH*NSEQ*DP;             // [BH][DP][NSEQ]
  float* oacc = (float*)(v + (size_t)BH*NSEQ*DP);        // [2][4096][768] fp32
  float* lacc = oacc + (size_t)2*MROWS*CDIM;             // [2][4096][16]  fp32

  prep<<<dim3(CONVB + 512), dim3(256), 0, stream>>>(x, qkv_w, proj_w, xb, q, k);
  qkv_gemm<<<dim3(MROWS/128, N3C/128), dim3(256), 0, stream>>>(xb, wb, qkv_b, q, k, v);
  attn<<<dim3(BH, NSEQ/128, 2), dim3(256), 0, stream>>>(q, k, v, oacc, lacc);
  proj_gemm<<<dim3(MROWS/64, CDIM/128), dim3(256), 0, stream>>>(oacc, lacc, pwb, proj_b, out);
}

// Round 12
// 174.388 us; speedup vs baseline: 1.0720x; 1.0720x over previous
//
#include <hip/hip_runtime.h>

typedef short v8s __attribute__((ext_vector_type(8)));
typedef short v4s __attribute__((ext_vector_type(4)));
typedef float v4f __attribute__((ext_vector_type(4)));
typedef unsigned uint2v __attribute__((ext_vector_type(2)));
typedef unsigned short u16;

#define NSEQ 2048
#define CDIM 768
#define NH   16
#define DH   48
#define DP   64
#define MROWS 4096      // B*N
#define N3C  2304
#define BH   32         // B*H

#if __has_builtin(__builtin_amdgcn_exp2f)
#define EXP2(x) __builtin_amdgcn_exp2f(x)
#else
#define EXP2(x) exp2f(x)
#endif
#if __has_builtin(__builtin_amdgcn_rcpf)
#define RCP(x) __builtin_amdgcn_rcpf(x)
#else
#define RCP(x) (1.0f/(x))
#endif

__device__ __forceinline__ u16 f2bf(float f){
  unsigned u = __float_as_uint(f);
  u += 0x7FFFu + ((u>>16)&1u);      // RNE; inputs finite
  return (u16)(u>>16);
}

#if __has_builtin(__builtin_amdgcn_cvt_pk_bf16_f32)
typedef __bf16 bf16x2_t __attribute__((ext_vector_type(2)));
__device__ __forceinline__ unsigned pkbf(float a, float b){   // [lo=a, hi=b], RNE, 1 inst
  bf16x2_t r = __builtin_amdgcn_cvt_pk_bf16_f32(a, b);
  return __builtin_bit_cast(unsigned, r);
}
#else
__device__ __forceinline__ unsigned pkbf(float a, float b){   // [lo=a, hi=b] bf16 pair, RNE
  unsigned x = __float_as_uint(a), y = __float_as_uint(b);
  x += 0x7FFFu + ((x>>16)&1u);
  y += 0x7FFFu + ((y>>16)&1u);
  return (x>>16) | (y & 0xFFFF0000u);
}
#endif

__device__ __forceinline__ void load_lds16(const u16* g, u16* l){
  __builtin_amdgcn_global_load_lds((const __attribute__((address_space(1))) void*)g,
                                   (__attribute__((address_space(3))) void*)l, 16, 0, 0);
}

// ---------------- K0: fused convert (x,qkv_w,proj_w -> bf16) + Q/K pad init ----------------
#define XN8  (MROWS*CDIM/8)                     // 393216
#define WN8  (N3C*CDIM/8)                       // 221184
#define PN8  (CDIM*CDIM/8)                      // 73728
#define CONVB ((XN8+WN8+PN8)/256)               // 2688 blocks
__global__ __launch_bounds__(256) void prep(const float* __restrict__ x, const float* __restrict__ w,
                                            const float* __restrict__ pw, u16* __restrict__ dst,
                                            u16* __restrict__ q, u16* __restrict__ k){
  int bid = blockIdx.x;
  if (bid < CONVB){
    int i = bid*256 + threadIdx.x;
    const float* src;
    if (i < XN8)            src = x  + (size_t)i*8;
    else if (i < XN8+WN8)   src = w  + (size_t)(i - XN8)*8;
    else                    src = pw + (size_t)(i - XN8 - WN8)*8;
    v4f f0 = ((const v4f*)src)[0];
    v4f f1 = ((const v4f*)src)[1];
    v8s o;
#pragma unroll
    for (int j = 0; j < 4; j++) ((u16*)&o)[j]   = f2bf(f0[j]);
#pragma unroll
    for (int j = 0; j < 4; j++) ((u16*)&o)[4+j] = f2bf(f1[j]);
    ((v8s*)dst)[i] = o;
  } else {
    int idx = (bid - CONVB)*256 + threadIdx.x;  // 512 blocks -> 131072 threads
    v8s z = (v8s){0,0,0,0,0,0,0,0};
    int r = idx >> 1, half = idx & 1;           // Q/K: 65536 rows, 2x16B pad per row
    *(v8s*)(q + (size_t)r*DP + DH + half*8) = z;
    *(v8s*)(k + (size_t)r*DP + DH + half*8) = z;
  }
}

// ================= K1: qkv GEMM, m97 structure (round-9 BK=32 version) =================
__global__ __launch_bounds__(256) void qkv_gemm(const u16* __restrict__ x, const u16* __restrict__ w,
                                                const float* __restrict__ bias,
                                                u16* __restrict__ q, u16* __restrict__ k, u16* __restrict__ v){
  __shared__ __align__(16) u16 As[128*32];
  __shared__ __align__(16) u16 Bs[128*32];
  const int wave = threadIdx.x >> 6;
  const int lane = threadIdx.x & 63;
  const int l15  = lane & 15;
  const int quad = lane >> 4;
  const int wm = wave & 1, wn = wave >> 1;
  const int m0 = blockIdx.x*128, n0 = blockIdx.y*128;

  const int srow = lane >> 2;
  const int sg   = (lane & 3) ^ ((lane >> 3) & 3);
  const int sgoff = sg*8;

  v4f acc[4][4];
#pragma unroll
  for (int i = 0; i < 4; i++)
#pragma unroll
    for (int j = 0; j < 4; j++) acc[i][j] = (v4f){0.f,0.f,0.f,0.f};

  const int sig = (l15 >> 1) & 3;

  for (int kt = 0; kt < CDIM/32; kt++){
    const int k0 = kt*32;
    __syncthreads();
#pragma unroll
    for (int j = 0; j < 2; j++){
      int c = wave*2 + j;
      int r = c*16 + srow;
      load_lds16(x + (size_t)(m0 + r)*CDIM + k0 + sgoff, &As[c*512]);
      load_lds16(w + (size_t)(n0 + r)*CDIM + k0 + sgoff, &Bs[c*512]);
    }
    __syncthreads();

    v8s af[4], bf[4];
#pragma unroll
    for (int t = 0; t < 4; t++){
      int ra = wm*64 + t*16 + l15;
      af[t] = *(const v8s*)(&As[ra*32 + ((quad ^ sig)<<3)]);
      int rb = wn*64 + t*16 + l15;
      bf[t] = *(const v8s*)(&Bs[rb*32 + ((quad ^ sig)<<3)]);
    }
#pragma unroll
    for (int ti = 0; ti < 4; ti++)
#pragma unroll
      for (int tj = 0; tj < 4; tj++)
        acc[ti][tj] = __builtin_amdgcn_mfma_f32_16x16x32_bf16(af[ti], bf[tj], acc[ti][tj], 0, 0, 0);
  }

  const float QS = 0.2082540589f;   // 1/sqrt(48) * log2(e)
#pragma unroll
  for (int tj = 0; tj < 4; tj++){
    const int c = n0 + wn*64 + tj*16 + l15;
    const float bv = bias[c];
    const int t = c / CDIM;
    const int rem = c - t*CDIM;
    const int h = rem / DH;
    const int d = rem - h*DH;
#pragma unroll
    for (int ti = 0; ti < 4; ti++){
#pragma unroll
      for (int r = 0; r < 4; r++){
        int m = m0 + wm*64 + ti*16 + quad*4 + r;
        int b_ = m >> 11;
        int n  = m & (NSEQ-1);
        float val = acc[ti][tj][r] + bv;
        if (t == 0) val *= QS;
        u16 o  = f2bf(val);
        int bhn = b_*NH + h;
        if (t == 0)      q[((size_t)bhn*NSEQ + n)*DP + d] = o;
        else if (t == 1) k[((size_t)bhn*NSEQ + n)*DP + d] = o;
        else             v[((size_t)bhn*DP + d)*NSEQ + n] = o;
      }
    }
  }
}

// ---------------- K2: flash attention, double-buffered staging, ONE barrier per tile ----------------
__global__ __launch_bounds__(256) void attn(const u16* __restrict__ q, const u16* __restrict__ k,
                                            const u16* __restrict__ v,
                                            float* __restrict__ oacc, float* __restrict__ lacc){
  __shared__ __align__(16) u16 Kl[2][64*64];    // 2x8 KB, [key][d] XOR-swizzled
  __shared__ __align__(16) u16 Vl[2][48*64];    // 2x6 KB, [d][key] rows 0..47
  __shared__ __align__(16) u16 Pl[4*2*1024];    // 16 KB, per-wave per-strip P tiles
  const int bh = blockIdx.x;
  const int qt = blockIdx.y;                    // 128-row Q tile
  const int sp = blockIdx.z;                    // key split 0/1
  const int wave = threadIdx.x >> 6;
  const int lane = threadIdx.x & 63;
  const int l15  = lane & 15;
  const int quad = lane >> 4;
  const int lo3  = l15 & 7;
  const u16* qb = q + (size_t)bh*NSEQ*DP;
  const u16* kb = k + (size_t)bh*NSEQ*DP;
  const u16* vb = v + (size_t)bh*DP*NSEQ;
  const int qm = qt*128 + wave*32;

  v8s qf[2][2];                                 // [strip][ks]
#pragma unroll
  for (int si = 0; si < 2; si++)
#pragma unroll
    for (int ks = 0; ks < 2; ks++)
      qf[si][ks] = *(const v8s*)(qb + (size_t)(qm + si*16 + l15)*DP + ks*32 + quad*8);

  const short one = (short)0x3F80;
  const v8s vones = (l15 == 0) ? (v8s){one,one,one,one,one,one,one,one}
                               : (v8s){0,0,0,0,0,0,0,0};

  v4f o[2][4];                   // [strip][dt]; dt3 col0 = rowsum
#pragma unroll
  for (int si = 0; si < 2; si++)
#pragma unroll
    for (int i = 0; i < 4; i++) o[si][i] = (v4f){0.f,0.f,0.f,0.f};

  const int sr  = lane >> 3;                    // 0..7
  const int soff = ((lane & 7) ^ (sr & 7)) * 8; // permuted 16B granule
  u16* Plw = Pl + wave*2048;

  // stage key-tile kt into buffer b (async DMA; no wait here)
  const int krow0 = wave*8 + sr;
#define STAGE(kt_, b_) do{                                                              \
    load_lds16(kb + ((size_t)((kt_)*64 + krow0))*DP + soff,      &Kl[b_][krow0*64]);    \
    load_lds16(kb + ((size_t)((kt_)*64 + 32 + krow0))*DP + soff, &Kl[b_][(32+krow0)*64]);\
    load_lds16(vb + (size_t)krow0*NSEQ + (kt_)*64 + soff,        &Vl[b_][krow0*64]);    \
    if (wave < 2)                                                                       \
      load_lds16(vb + (size_t)(32+krow0)*NSEQ + (kt_)*64 + soff, &Vl[b_][(32+krow0)*64]);\
  } while(0)

  STAGE(sp*16, 0);

  for (int i = 0; i < 16; i++){
    const int buf = i & 1;
    __syncthreads();                            // publishes buf; drains are overlapped by compute
    if (i < 15) STAGE(sp*16 + i + 1, buf^1);    // prefetch next tile into other buffer

    const u16* Klb = &Kl[buf][0];
    const u16* Vlb = &Vl[buf][0];

    // S^T = K Q^T for both strips; each K fragment read once
    v4f s[2][4];
#pragma unroll
    for (int nt = 0; nt < 4; nt++){
      int rrow = nt*16 + l15;
      v8s kf0 = *(const v8s*)(&Klb[rrow*64 + ((quad ^ lo3)<<3)]);
      v8s kf1 = *(const v8s*)(&Klb[rrow*64 + (((4+quad) ^ lo3)<<3)]);
      s[0][nt] = __builtin_amdgcn_mfma_f32_16x16x32_bf16(kf0, qf[0][0], (v4f){0.f,0.f,0.f,0.f}, 0, 0, 0);
      s[0][nt] = __builtin_amdgcn_mfma_f32_16x16x32_bf16(kf1, qf[0][1], s[0][nt], 0, 0, 0);
      s[1][nt] = __builtin_amdgcn_mfma_f32_16x16x32_bf16(kf0, qf[1][0], (v4f){0.f,0.f,0.f,0.f}, 0, 0, 0);
      s[1][nt] = __builtin_amdgcn_mfma_f32_16x16x32_bf16(kf1, qf[1][1], s[1][nt], 0, 0, 0);
    }

    // P = exp2(S^T) -> bf16 pairs (hw pk convert), b64 writes
#pragma unroll
    for (int si = 0; si < 2; si++)
#pragma unroll
      for (int nt = 0; nt < 4; nt++){
        uint2v pw;
        pw.x = pkbf(EXP2(s[si][nt][0]), EXP2(s[si][nt][1]));
        pw.y = pkbf(EXP2(s[si][nt][2]), EXP2(s[si][nt][3]));
        int g = nt*2 + (quad>>1);
        *(uint2v*)(&Plw[si*1024 + l15*64 + ((g ^ lo3)<<3) + (quad&1)*4]) = pw;
      }

    // O += P V  (V fragments shared by both strips); dt3 via constant ones-frag
    v8s pa[2][2];
#pragma unroll
    for (int si = 0; si < 2; si++)
#pragma unroll
      for (int ks = 0; ks < 2; ks++){
        int ga = ks*4 + quad;
        pa[si][ks] = *(const v8s*)(&Plw[si*1024 + l15*64 + ((ga ^ lo3)<<3)]);
      }
#pragma unroll
    for (int dt = 0; dt < 3; dt++){
#pragma unroll
      for (int ks = 0; ks < 2; ks++){
        int row = dt*16 + l15;
        v8s vf = *(const v8s*)(&Vlb[row*64 + (((ks*4+quad) ^ lo3)<<3)]);
        o[0][dt] = __builtin_amdgcn_mfma_f32_16x16x32_bf16(pa[0][ks], vf, o[0][dt], 0, 0, 0);
        o[1][dt] = __builtin_amdgcn_mfma_f32_16x16x32_bf16(pa[1][ks], vf, o[1][dt], 0, 0, 0);
      }
    }
#pragma unroll
    for (int ks = 0; ks < 2; ks++){
      o[0][3] = __builtin_amdgcn_mfma_f32_16x16x32_bf16(pa[0][ks], vones, o[0][3], 0, 0, 0);
      o[1][3] = __builtin_amdgcn_mfma_f32_16x16x32_bf16(pa[1][ks], vones, o[1][3], 0, 0, 0);
    }
  }

  const int b_ = bh / NH, h = bh % NH;
  float* oa = oacc + (size_t)sp*MROWS*CDIM;
  float* la = lacc + (size_t)sp*MROWS*NH;
#pragma unroll
  for (int si = 0; si < 2; si++){
#pragma unroll
    for (int r = 0; r < 4; r++){
      int rowg = b_*NSEQ + qm + si*16 + quad*4 + r;
#pragma unroll
      for (int dt = 0; dt < 3; dt++)
        oa[(size_t)rowg*CDIM + h*DH + dt*16 + l15] = o[si][dt][r];
      if (l15 == 0) la[rowg*NH + h] = o[si][3][r];  // rowsum at col 0 of dt3
    }
  }
}

// ---------------- K2b: combine splits, normalize, emit bf16 y ----------------
__global__ __launch_bounds__(256) void finalize(const float* __restrict__ oacc,
                                                const float* __restrict__ lacc,
                                                u16* __restrict__ y){
  int i = blockIdx.x*256 + threadIdx.x;         // 4096*192 threads, 4 cols each
  int rowg = i / 192, c4 = i - rowg*192;
  int c = c4*4, h = c / DH;                     // float4 never crosses an h block
  float l = lacc[rowg*NH + h] + lacc[MROWS*NH + rowg*NH + h];
  float inv = RCP(l);
  v4f a = *(const v4f*)(oacc + (size_t)rowg*CDIM + c);
  v4f b = *(const v4f*)(oacc + (size_t)MROWS*CDIM + (size_t)rowg*CDIM + c);
  v4s o4;
#pragma unroll
  for (int j = 0; j < 4; j++) o4[j] = (short)f2bf((a[j] + b[j])*inv);
  *(v4s*)(y + (size_t)rowg*CDIM + c) = o4;
}

// ================= K3: proj GEMM, m97 structure, 64x128 tile (round-9 version) =================
__global__ __launch_bounds__(256) void proj_gemm(const u16* __restrict__ y, const u16* __restrict__ w,
                                                 const float* __restrict__ bias, float* __restrict__ out){
  __shared__ __align__(16) u16 As[64*32];
  __shared__ __align__(16) u16 Bs[128*32];
  const int wave = threadIdx.x >> 6;
  const int lane = threadIdx.x & 63;
  const int l15  = lane & 15;
  const int quad = lane >> 4;
  const int wm = wave & 1, wn = wave >> 1;
  const int m0 = blockIdx.x*64, n0 = blockIdx.y*128;

  const int srow = lane >> 2;
  const int sg   = (lane & 3) ^ ((lane >> 3) & 3);
  const int sgoff = sg*8;

  v4f acc[2][4];
#pragma unroll
  for (int i = 0; i < 2; i++)
#pragma unroll
    for (int j = 0; j < 4; j++) acc[i][j] = (v4f){0.f,0.f,0.f,0.f};

  const int sig = (l15 >> 1) & 3;

  for (int kt = 0; kt < CDIM/32; kt++){
    const int k0 = kt*32;
    __syncthreads();
    {
      int rA = wave*16 + srow;
      load_lds16(y + (size_t)(m0 + rA)*CDIM + k0 + sgoff, &As[wave*512]);
#pragma unroll
      for (int j = 0; j < 2; j++){
        int c = wave*2 + j;
        int rB = c*16 + srow;
        load_lds16(w + (size_t)(n0 + rB)*CDIM + k0 + sgoff, &Bs[c*512]);
      }
    }
    __syncthreads();

    v8s af[2], bf[4];
#pragma unroll
    for (int t = 0; t < 2; t++){
      int ra = wm*32 + t*16 + l15;
      af[t] = *(const v8s*)(&As[ra*32 + ((quad ^ sig)<<3)]);
    }
#pragma unroll
    for (int t = 0; t < 4; t++){
      int rb = wn*64 + t*16 + l15;
      bf[t] = *(const v8s*)(&Bs[rb*32 + ((quad ^ sig)<<3)]);
    }
#pragma unroll
    for (int ti = 0; ti < 2; ti++)
#pragma unroll
      for (int tj = 0; tj < 4; tj++)
        acc[ti][tj] = __builtin_amdgcn_mfma_f32_16x16x32_bf16(af[ti], bf[tj], acc[ti][tj], 0, 0, 0);
  }

#pragma unroll
  for (int tj = 0; tj < 4; tj++){
    const int c = n0 + wn*64 + tj*16 + l15;
    const float bv = bias[c];
#pragma unroll
    for (int ti = 0; ti < 2; ti++){
#pragma unroll
      for (int r = 0; r < 4; r++){
        int m = m0 + wm*32 + ti*16 + quad*4 + r;
        out[(size_t)m*CDIM + c] = acc[ti][tj][r] + bv;
      }
    }
  }
}

extern "C" void kernel_launch(void* const* d_in, const int* in_sizes, int n_in,
                              void* d_out, int out_size, void* d_ws, size_t ws_size,
                              hipStream_t stream){
  const float* x      = (const float*)d_in[0];
  const float* qkv_w  = (const float*)d_in[1];
  const float* qkv_b  = (const float*)d_in[2];
  const float* proj_w = (const float*)d_in[3];
  const float* proj_b = (const float*)d_in[4];
  float* out = (float*)d_out;

  // ws layout (u16 units); y reuses xb's region (x dead after qkv)
  u16* xb  = (u16*)d_ws;                         // [4096][768] bf16, later y
  u16* wb  = xb  + (size_t)MROWS*CDIM;           // [2304][768] bf16
  u16* pwb = wb  + (size_t)N3C*CDIM;             // [768][768]  bf16
  u16* q   = pwb + (size_t)CDIM*CDIM;            // [BH][NSEQ][DP]
  u16* k   = q + (size_t)BH*NSEQ*DP;
  u16* v   = k + (size_t)BH*NSEQ*DP;             // [BH][DP][NSEQ]
  float* oacc = (float*)(v + (size_t)BH*NSEQ*DP);        // [2][4096][768] fp32
  float* lacc = oacc + (size_t)2*MROWS*CDIM;             // [2][4096][16]  fp32
  u16* y = xb;

  prep<<<dim3(CONVB + 512), dim3(256), 0, stream>>>(x, qkv_w, proj_w, xb, q, k);
  qkv_gemm<<<dim3(MROWS/128, N3C/128), dim3(256), 0, stream>>>(xb, wb, qkv_b, q, k, v);
  attn<<<dim3(BH, NSEQ/128, 2), dim3(256), 0, stream>>>(q, k, v, oacc, lacc);
  finalize<<<dim3(MROWS*192/256), dim3(256), 0, stream>>>(oacc, lacc, y);
  proj_gemm<<<dim3(MROWS/64, CDIM/128), dim3(256), 0, stream>>>(y, pwb, proj_b, out);
}